// Round 2
// baseline (1537.800 us; speedup 1.0000x reference)
//
#include <hip/hip_runtime.h>
#include <math.h>

#define NHEAD 8
#define DMODEL 256
#define DKV 32
#define BATCH 2
#define LSEQ 1024
#define LN_EPS 1e-5f
#define INV_SQRT_DK 0.17677669529663687f

// ---------------- Kernel A: LayerNorm stats (mu, rsigma per row) ----------------
__global__ void ln_stats_kernel(const float* __restrict__ hin, float* __restrict__ stats) {
  int row = blockIdx.x;
  int t = threadIdx.x;
  float x = hin[(size_t)row * DMODEL + t];
  float s = x, ss = x * x;
#pragma unroll
  for (int off = 32; off > 0; off >>= 1) {
    s += __shfl_xor(s, off);
    ss += __shfl_xor(ss, off);
  }
  __shared__ float red[8];
  int wave = t >> 6, lane = t & 63;
  if (lane == 0) { red[wave] = s; red[4 + wave] = ss; }
  __syncthreads();
  if (t == 0) {
    float S = red[0] + red[1] + red[2] + red[3];
    float SS = red[4] + red[5] + red[6] + red[7];
    float mu = S * (1.0f / DMODEL);
    float var = SS * (1.0f / DMODEL) - mu * mu;
    stats[row * 2] = mu;
    stats[row * 2 + 1] = rsqrtf(var + LN_EPS);
  }
}

// ---------------- Kernel B: QKV projection GEMM with fused LayerNorm ----------------
// q output: row-major (b*L, 256).  k/v outputs: TRANSPOSED per batch: [b][channel][j]
#define BM 64
#define BN 64
#define BK 16
__global__ void qkv_gemm_kernel(const float* __restrict__ hin, const float* __restrict__ stats,
                                const float* __restrict__ ln_g, const float* __restrict__ ln_b,
                                const float* __restrict__ w_qs, const float* __restrict__ w_ks,
                                const float* __restrict__ w_vs,
                                float* __restrict__ q_ws, float* __restrict__ kT,
                                float* __restrict__ vT) {
  __shared__ float As[BK][BM + 4];
  __shared__ float Bs[BK][BN + 4];
  int m0 = blockIdx.x * BM;
  int nb = blockIdx.y;             // 0..11
  int mat = nb >> 2;               // 0:q 1:k 2:v
  int n0 = (nb & 3) * BN;
  const float* W = (mat == 0) ? w_qs : (mat == 1 ? w_ks : w_vs);
  int t = threadIdx.x;
  int tx = t & 15, ty = t >> 4;
  int lr = t >> 2, lc = (t & 3) * 4;
  float mu = stats[(m0 + lr) * 2];
  float rs = stats[(m0 + lr) * 2 + 1];
  float acc[4][4] = {};
  for (int k0 = 0; k0 < DMODEL; k0 += BK) {
    __syncthreads();
    float4 a = *(const float4*)&hin[(size_t)(m0 + lr) * DMODEL + k0 + lc];
    float4 g = *(const float4*)&ln_g[k0 + lc];
    float4 bb = *(const float4*)&ln_b[k0 + lc];
    As[lc + 0][lr] = (a.x - mu) * rs * g.x + bb.x;
    As[lc + 1][lr] = (a.y - mu) * rs * g.y + bb.y;
    As[lc + 2][lr] = (a.z - mu) * rs * g.z + bb.z;
    As[lc + 3][lr] = (a.w - mu) * rs * g.w + bb.w;
    float4 w = *(const float4*)&W[(size_t)(n0 + lr) * DMODEL + k0 + lc];
    Bs[lc + 0][lr] = w.x;
    Bs[lc + 1][lr] = w.y;
    Bs[lc + 2][lr] = w.z;
    Bs[lc + 3][lr] = w.w;
    __syncthreads();
#pragma unroll
    for (int kk = 0; kk < BK; kk++) {
      float4 av = *(const float4*)&As[kk][ty * 4];
      float4 bv = *(const float4*)&Bs[kk][tx * 4];
      float am[4] = {av.x, av.y, av.z, av.w};
      float bm[4] = {bv.x, bv.y, bv.z, bv.w};
#pragma unroll
      for (int ii = 0; ii < 4; ii++)
#pragma unroll
        for (int jj = 0; jj < 4; jj++) acc[ii][jj] += am[ii] * bm[jj];
    }
  }
  if (mat == 0) {
#pragma unroll
    for (int ii = 0; ii < 4; ii++) {
      float4 st = {acc[ii][0], acc[ii][1], acc[ii][2], acc[ii][3]};
      *(float4*)&q_ws[(size_t)(m0 + ty * 4 + ii) * DMODEL + n0 + tx * 4] = st;
    }
  } else {
    float* O = (mat == 1) ? kT : vT;
    int bb2 = m0 >> 10;                 // BM=64 divides 1024: whole block same batch
    int jbase = (m0 & 1023) + ty * 4;
    float* Ob = O + (size_t)bb2 * DMODEL * LSEQ;
#pragma unroll
    for (int jj = 0; jj < 4; jj++) {
      int n = n0 + tx * 4 + jj;
      float4 st = {acc[0][jj], acc[1][jj], acc[2][jj], acc[3][jj]};
      *(float4*)&Ob[(size_t)n * LSEQ + jbase] = st;
    }
  }
}

// ---------------- Kernel C: fused attention per (b,i) row ----------------
// One block (256 thr) per (b,i). thread = (head hh = t>>5, j-lane jl = t&31).
// K/V TRANSPOSED [b][c][j]: lane jl owns 4 consecutive j -> coalesced loads.
// Bias tile (128 j x 32 d) staged TRANSPOSED into DOUBLE-BUFFERED LDS
// (short-lived reg staging -> no spill; one barrier per tile).
// p written UNNORMALIZED to attn_out in-loop, rescaled in place afterwards
// (frees the 32KB LDS p region -> 34.8 KB LDS -> 4 blocks/CU).
// LDS: biasT buf0 [0,4224), buf1 [4224,8448); scratch [8][32][33] overlaps
// [0,8448) after the loop; emb vector 256 f at 8448. Total 8704 f = 34816 B.
#define JTILE 128
#define NTILE 8
#define BIASLD 132
#define TILE_F (32 * BIASLD)
#define EMB_OFF (2 * TILE_F)
#define SMEM_FLOATS (2 * TILE_F + 256)

__global__ __launch_bounds__(256, 4) void attn_kernel(
    const float* __restrict__ q_ws, const float* __restrict__ kT,
    const float* __restrict__ vT, const float* __restrict__ bias,
    const float* __restrict__ hin, const float* __restrict__ fc_w,
    const float* __restrict__ fc_b, float* __restrict__ out,
    float* __restrict__ attn_out) {
  __shared__ float smem[SMEM_FLOATS];
  int blk = blockIdx.x;
  int b = blk >> 10, i = blk & 1023;
  int t = threadIdx.x;
  int hh = t >> 5, jl = t & 31;
  const float* bias_row = bias + (size_t)blk * (LSEQ * DKV);
  const float* kb = kT + ((size_t)b * DMODEL + hh * DKV) * LSEQ;
  const float* vb = vT + ((size_t)b * DMODEL + hh * DKV) * LSEQ;
  float* arow = attn_out + (((size_t)hh * BATCH + b) * LSEQ + i) * LSEQ;

  float q[32];
  {
    const float4* qp = (const float4*)(q_ws + (size_t)blk * DMODEL + hh * DKV);
#pragma unroll
    for (int c = 0; c < 8; c++) {
      float4 v4 = qp[c];
      q[4 * c + 0] = v4.x; q[4 * c + 1] = v4.y;
      q[4 * c + 2] = v4.z; q[4 * c + 3] = v4.w;
    }
  }
  float acc[32];
#pragma unroll
  for (int d = 0; d < 32; d++) acc[d] = 0.f;
  float l_part = 0.f;

  // prologue: stage tile 0 into buf0 (transpose [j][d] -> biasT[d][j])
  {
    float4 s0 = *(const float4*)(bias_row + (size_t)t * 4);
    float4 s1 = *(const float4*)(bias_row + (size_t)(256 + t) * 4);
    float4 s2 = *(const float4*)(bias_row + (size_t)(512 + t) * 4);
    float4 s3 = *(const float4*)(bias_row + (size_t)(768 + t) * 4);
    int jr, d0;
    jr = t >> 3; d0 = (t & 7) * 4;
    smem[(d0 + 0) * BIASLD + jr] = s0.x; smem[(d0 + 1) * BIASLD + jr] = s0.y;
    smem[(d0 + 2) * BIASLD + jr] = s0.z; smem[(d0 + 3) * BIASLD + jr] = s0.w;
    jr = (256 + t) >> 3; d0 = (t & 7) * 4;
    smem[(d0 + 0) * BIASLD + jr] = s1.x; smem[(d0 + 1) * BIASLD + jr] = s1.y;
    smem[(d0 + 2) * BIASLD + jr] = s1.z; smem[(d0 + 3) * BIASLD + jr] = s1.w;
    jr = (512 + t) >> 3; d0 = (t & 7) * 4;
    smem[(d0 + 0) * BIASLD + jr] = s2.x; smem[(d0 + 1) * BIASLD + jr] = s2.y;
    smem[(d0 + 2) * BIASLD + jr] = s2.z; smem[(d0 + 3) * BIASLD + jr] = s2.w;
    jr = (768 + t) >> 3; d0 = (t & 7) * 4;
    smem[(d0 + 0) * BIASLD + jr] = s3.x; smem[(d0 + 1) * BIASLD + jr] = s3.y;
    smem[(d0 + 2) * BIASLD + jr] = s3.z; smem[(d0 + 3) * BIASLD + jr] = s3.w;
  }
  __syncthreads();

  for (int jt = 0; jt < NTILE; jt++) {
    const float* bufc = smem + (jt & 1) * TILE_F;
    // issue next tile's global loads early (short-lived regs, no barrier crossing
    // of a long compute for the *values* -- writes land right before the barrier)
    float4 n0, n1, n2, n3;
    if (jt + 1 < NTILE) {
      const float* src = bias_row + (size_t)(jt + 1) * 4096;
      n0 = *(const float4*)(src + (size_t)t * 4);
      n1 = *(const float4*)(src + (size_t)(256 + t) * 4);
      n2 = *(const float4*)(src + (size_t)(512 + t) * 4);
      n3 = *(const float4*)(src + (size_t)(768 + t) * 4);
    }
    int j0 = jt * JTILE + jl * 4;
    const float* kp = kb + j0;
    const float* vp = vb + j0;
    float s0 = 0.f, s1 = 0.f, s2 = 0.f, s3 = 0.f;
#pragma unroll
    for (int d = 0; d < 32; d++) {
      float4 kv = *(const float4*)(kp + (size_t)d * LSEQ);
      float4 bb = *(const float4*)&bufc[d * BIASLD + jl * 4];
      s0 += q[d] * (kv.x + bb.x);
      s1 += q[d] * (kv.y + bb.y);
      s2 += q[d] * (kv.z + bb.z);
      s3 += q[d] * (kv.w + bb.w);
    }
    float p0 = __expf(s0 * INV_SQRT_DK);
    float p1 = __expf(s1 * INV_SQRT_DK);
    float p2 = __expf(s2 * INV_SQRT_DK);
    float p3 = __expf(s3 * INV_SQRT_DK);
    l_part += (p0 + p1) + (p2 + p3);
    *(float4*)&arow[j0] = make_float4(p0, p1, p2, p3);  // unnormalized, rescaled later
#pragma unroll
    for (int d = 0; d < 32; d++) {
      float4 vv = *(const float4*)(vp + (size_t)d * LSEQ);
      float4 bb = *(const float4*)&bufc[d * BIASLD + jl * 4];
      acc[d] += p0 * (vv.x + bb.x) + p1 * (vv.y + bb.y) +
                p2 * (vv.z + bb.z) + p3 * (vv.w + bb.w);
    }
    if (jt + 1 < NTILE) {
      float* bufn = smem + ((jt + 1) & 1) * TILE_F;
      int jr, d0;
      jr = t >> 3; d0 = (t & 7) * 4;
      bufn[(d0 + 0) * BIASLD + jr] = n0.x; bufn[(d0 + 1) * BIASLD + jr] = n0.y;
      bufn[(d0 + 2) * BIASLD + jr] = n0.z; bufn[(d0 + 3) * BIASLD + jr] = n0.w;
      jr = (256 + t) >> 3; d0 = (t & 7) * 4;
      bufn[(d0 + 0) * BIASLD + jr] = n1.x; bufn[(d0 + 1) * BIASLD + jr] = n1.y;
      bufn[(d0 + 2) * BIASLD + jr] = n1.z; bufn[(d0 + 3) * BIASLD + jr] = n1.w;
      jr = (512 + t) >> 3; d0 = (t & 7) * 4;
      bufn[(d0 + 0) * BIASLD + jr] = n2.x; bufn[(d0 + 1) * BIASLD + jr] = n2.y;
      bufn[(d0 + 2) * BIASLD + jr] = n2.z; bufn[(d0 + 3) * BIASLD + jr] = n2.w;
      jr = (768 + t) >> 3; d0 = (t & 7) * 4;
      bufn[(d0 + 0) * BIASLD + jr] = n3.x; bufn[(d0 + 1) * BIASLD + jr] = n3.y;
      bufn[(d0 + 2) * BIASLD + jr] = n3.z; bufn[(d0 + 3) * BIASLD + jr] = n3.w;
    }
    __syncthreads();
  }

  // per-head softmax denominator: reduce over the 32 jl lanes (half-wave)
  float l = l_part;
#pragma unroll
  for (int off = 16; off > 0; off >>= 1) l += __shfl_xor(l, off);
  float inv_l = 1.0f / l;

  // rescale own p values in place (L2-warm: just written by this thread)
#pragma unroll
  for (int c = 0; c < 8; c++) {
    int jc = c * 128 + jl * 4;
    float4 pv = *(const float4*)&arow[jc];
    pv.x *= inv_l; pv.y *= inv_l; pv.z *= inv_l; pv.w *= inv_l;
    *(float4*)&arow[jc] = pv;
  }

  // cross-lane reduction of emb partials: scratch[h][d][33] overlapping bias bufs
  // (loop's final barrier guarantees all waves are done reading biasT)
#pragma unroll
  for (int d = 0; d < 32; d++)
    smem[hh * 1056 + d * 33 + jl] = acc[d] * inv_l;
  __syncthreads();
  float emb = 0.f;
  {
    const float* base = &smem[(t >> 5) * 1056 + (t & 31) * 33];
#pragma unroll
    for (int r = 0; r < 32; r++) emb += base[r];
  }
  __syncthreads();
  smem[EMB_OFF + t] = emb;  // emb vector (h*32+d ordering == fc input ordering)
  __syncthreads();

  // FC + bias + residual: thread t = output channel
  float o = fc_b[t];
  const float4* wrow = (const float4*)(fc_w + (size_t)t * DMODEL);
#pragma unroll
  for (int c = 0; c < 64; c++) {
    float4 wv = wrow[c];
    float4 ev = *(const float4*)&smem[EMB_OFF + c * 4];
    o += wv.x * ev.x + wv.y * ev.y + wv.z * ev.z + wv.w * ev.w;
  }
  o += hin[(size_t)blk * DMODEL + t];
  out[(size_t)blk * DMODEL + t] = o;
}

extern "C" void kernel_launch(void* const* d_in, const int* in_sizes, int n_in,
                              void* d_out, int out_size, void* d_ws, size_t ws_size,
                              hipStream_t stream) {
  const float* h = (const float*)d_in[0];
  const float* bias = (const float*)d_in[1];
  const float* w_qs = (const float*)d_in[2];
  const float* w_ks = (const float*)d_in[3];
  const float* w_vs = (const float*)d_in[4];
  const float* ln_g = (const float*)d_in[5];
  const float* ln_b = (const float*)d_in[6];
  const float* fc_w = (const float*)d_in[7];
  const float* fc_b = (const float*)d_in[8];
  float* out = (float*)d_out;
  float* attn_out = out + (size_t)BATCH * LSEQ * DMODEL;  // tuple: (out, attn)

  float* ws = (float*)d_ws;
  float* stats = ws;                                    // 4096 floats
  float* q_ws = ws + 4096;                              // 2048*256
  float* kT = q_ws + (size_t)BATCH * LSEQ * DMODEL;     // 2*256*1024 (transposed)
  float* vT = kT + (size_t)BATCH * LSEQ * DMODEL;       // 2*256*1024 (transposed)

  ln_stats_kernel<<<BATCH * LSEQ, 256, 0, stream>>>(h, stats);
  qkv_gemm_kernel<<<dim3(32, 12), 256, 0, stream>>>(h, stats, ln_g, ln_b, w_qs, w_ks,
                                                    w_vs, q_ws, kT, vT);
  attn_kernel<<<BATCH * LSEQ, 256, 0, stream>>>(q_ws, kT, vT, bias, h, fc_w, fc_b,
                                                out, attn_out);
}

// Round 3
// 707.720 us; speedup vs baseline: 2.1729x; 2.1729x over previous
//
#include <hip/hip_runtime.h>
#include <math.h>

#define NHEAD 8
#define DMODEL 256
#define DKV 32
#define BATCH 2
#define LSEQ 1024
#define LN_EPS 1e-5f
#define INV_SQRT_DK 0.17677669529663687f

// ---------------- Kernel A: LayerNorm stats (mu, rsigma per row) ----------------
__global__ void ln_stats_kernel(const float* __restrict__ hin, float* __restrict__ stats) {
  int row = blockIdx.x;
  int t = threadIdx.x;
  float x = hin[(size_t)row * DMODEL + t];
  float s = x, ss = x * x;
#pragma unroll
  for (int off = 32; off > 0; off >>= 1) {
    s += __shfl_xor(s, off);
    ss += __shfl_xor(ss, off);
  }
  __shared__ float red[8];
  int wave = t >> 6, lane = t & 63;
  if (lane == 0) { red[wave] = s; red[4 + wave] = ss; }
  __syncthreads();
  if (t == 0) {
    float S = red[0] + red[1] + red[2] + red[3];
    float SS = red[4] + red[5] + red[6] + red[7];
    float mu = S * (1.0f / DMODEL);
    float var = SS * (1.0f / DMODEL) - mu * mu;
    stats[row * 2] = mu;
    stats[row * 2 + 1] = rsqrtf(var + LN_EPS);
  }
}

// ---------------- Kernel B: QKV projection GEMM with fused LayerNorm ----------------
// q output: row-major (b*L, 256).  k/v outputs: TRANSPOSED per batch: [b][channel][j]
#define BM 64
#define BN 64
#define BK 16
__global__ void qkv_gemm_kernel(const float* __restrict__ hin, const float* __restrict__ stats,
                                const float* __restrict__ ln_g, const float* __restrict__ ln_b,
                                const float* __restrict__ w_qs, const float* __restrict__ w_ks,
                                const float* __restrict__ w_vs,
                                float* __restrict__ q_ws, float* __restrict__ kT,
                                float* __restrict__ vT) {
  __shared__ float As[BK][BM + 4];
  __shared__ float Bs[BK][BN + 4];
  int m0 = blockIdx.x * BM;
  int nb = blockIdx.y;             // 0..11
  int mat = nb >> 2;               // 0:q 1:k 2:v
  int n0 = (nb & 3) * BN;
  const float* W = (mat == 0) ? w_qs : (mat == 1 ? w_ks : w_vs);
  int t = threadIdx.x;
  int tx = t & 15, ty = t >> 4;
  int lr = t >> 2, lc = (t & 3) * 4;
  float mu = stats[(m0 + lr) * 2];
  float rs = stats[(m0 + lr) * 2 + 1];
  float acc[4][4] = {};
  for (int k0 = 0; k0 < DMODEL; k0 += BK) {
    __syncthreads();
    float4 a = *(const float4*)&hin[(size_t)(m0 + lr) * DMODEL + k0 + lc];
    float4 g = *(const float4*)&ln_g[k0 + lc];
    float4 bb = *(const float4*)&ln_b[k0 + lc];
    As[lc + 0][lr] = (a.x - mu) * rs * g.x + bb.x;
    As[lc + 1][lr] = (a.y - mu) * rs * g.y + bb.y;
    As[lc + 2][lr] = (a.z - mu) * rs * g.z + bb.z;
    As[lc + 3][lr] = (a.w - mu) * rs * g.w + bb.w;
    float4 w = *(const float4*)&W[(size_t)(n0 + lr) * DMODEL + k0 + lc];
    Bs[lc + 0][lr] = w.x;
    Bs[lc + 1][lr] = w.y;
    Bs[lc + 2][lr] = w.z;
    Bs[lc + 3][lr] = w.w;
    __syncthreads();
#pragma unroll
    for (int kk = 0; kk < BK; kk++) {
      float4 av = *(const float4*)&As[kk][ty * 4];
      float4 bv = *(const float4*)&Bs[kk][tx * 4];
      float am[4] = {av.x, av.y, av.z, av.w};
      float bm[4] = {bv.x, bv.y, bv.z, bv.w};
#pragma unroll
      for (int ii = 0; ii < 4; ii++)
#pragma unroll
        for (int jj = 0; jj < 4; jj++) acc[ii][jj] += am[ii] * bm[jj];
    }
  }
  if (mat == 0) {
#pragma unroll
    for (int ii = 0; ii < 4; ii++) {
      float4 st = {acc[ii][0], acc[ii][1], acc[ii][2], acc[ii][3]};
      *(float4*)&q_ws[(size_t)(m0 + ty * 4 + ii) * DMODEL + n0 + tx * 4] = st;
    }
  } else {
    float* O = (mat == 1) ? kT : vT;
    int bb2 = m0 >> 10;                 // BM=64 divides 1024: whole block same batch
    int jbase = (m0 & 1023) + ty * 4;
    float* Ob = O + (size_t)bb2 * DMODEL * LSEQ;
#pragma unroll
    for (int jj = 0; jj < 4; jj++) {
      int n = n0 + tx * 4 + jj;
      float4 st = {acc[0][jj], acc[1][jj], acc[2][jj], acc[3][jj]};
      *(float4*)&Ob[(size_t)n * LSEQ + jbase] = st;
    }
  }
}

// ---------------- Kernel C: fused attention per (b,i) row ----------------
// One block (256 thr) per (b,i). thread = (head hh = t>>5, j-lane jl = t&31).
// K/V TRANSPOSED [b][c][j]: lane jl owns 4 consecutive j -> coalesced loads.
// Bias tile (128 j x 32 d) staged TRANSPOSED into DOUBLE-BUFFERED LDS.
// q lives in LDS (broadcast reads) -> frees 32 VGPRs; NO launch_bounds min-waves
// hint (r1/r2 showed it forces spill: VGPR 84/64 with 0.3-4GB scratch traffic).
// p written UNNORMALIZED to attn_out in-loop, rescaled in place afterwards.
// LDS: biasT buf0 [0,4224), buf1 [4224,8448); scratch [8][32][33] overlaps
// [0,8448) after the loop; emb 256 f at 8448; q [8][33] at 8704.
// Total 8968 f = 35872 B -> 4 blocks/CU if VGPR <= 128.
#define JTILE 128
#define NTILE 8
#define BIASLD 132
#define TILE_F (32 * BIASLD)
#define EMB_OFF (2 * TILE_F)
#define Q_OFF (EMB_OFF + 256)
#define SMEM_FLOATS (Q_OFF + 8 * 33)

__global__ __launch_bounds__(256) void attn_kernel(
    const float* __restrict__ q_ws, const float* __restrict__ kT,
    const float* __restrict__ vT, const float* __restrict__ bias,
    const float* __restrict__ hin, const float* __restrict__ fc_w,
    const float* __restrict__ fc_b, float* __restrict__ out,
    float* __restrict__ attn_out) {
  __shared__ float smem[SMEM_FLOATS];
  int blk = blockIdx.x;
  int b = blk >> 10, i = blk & 1023;
  int t = threadIdx.x;
  int hh = t >> 5, jl = t & 31;
  const float* bias_row = bias + (size_t)blk * (LSEQ * DKV);
  const float* kb = kT + ((size_t)b * DMODEL + hh * DKV) * LSEQ;
  const float* vb = vT + ((size_t)b * DMODEL + hh * DKV) * LSEQ;
  float* arow = attn_out + (((size_t)hh * BATCH + b) * LSEQ + i) * LSEQ;

  // q -> LDS, padded [h][33]: per-half-wave broadcast reads, conflict-free
  smem[Q_OFF + (t >> 5) * 33 + (t & 31)] = q_ws[(size_t)blk * DMODEL + t];

  float acc[32];
#pragma unroll
  for (int d = 0; d < 32; d++) acc[d] = 0.f;
  float l_part = 0.f;

  // prologue: stage tile 0 into buf0 (transpose [j][d] -> biasT[d][j])
  {
    float4 s0 = *(const float4*)(bias_row + (size_t)t * 4);
    float4 s1 = *(const float4*)(bias_row + (size_t)(256 + t) * 4);
    float4 s2 = *(const float4*)(bias_row + (size_t)(512 + t) * 4);
    float4 s3 = *(const float4*)(bias_row + (size_t)(768 + t) * 4);
    int jr, d0;
    jr = t >> 3; d0 = (t & 7) * 4;
    smem[(d0 + 0) * BIASLD + jr] = s0.x; smem[(d0 + 1) * BIASLD + jr] = s0.y;
    smem[(d0 + 2) * BIASLD + jr] = s0.z; smem[(d0 + 3) * BIASLD + jr] = s0.w;
    jr = (256 + t) >> 3;
    smem[(d0 + 0) * BIASLD + jr] = s1.x; smem[(d0 + 1) * BIASLD + jr] = s1.y;
    smem[(d0 + 2) * BIASLD + jr] = s1.z; smem[(d0 + 3) * BIASLD + jr] = s1.w;
    jr = (512 + t) >> 3;
    smem[(d0 + 0) * BIASLD + jr] = s2.x; smem[(d0 + 1) * BIASLD + jr] = s2.y;
    smem[(d0 + 2) * BIASLD + jr] = s2.z; smem[(d0 + 3) * BIASLD + jr] = s2.w;
    jr = (768 + t) >> 3;
    smem[(d0 + 0) * BIASLD + jr] = s3.x; smem[(d0 + 1) * BIASLD + jr] = s3.y;
    smem[(d0 + 2) * BIASLD + jr] = s3.z; smem[(d0 + 3) * BIASLD + jr] = s3.w;
  }
  __syncthreads();

  const float* qsh = &smem[Q_OFF + hh * 33];

  for (int jt = 0; jt < NTILE; jt++) {
    const float* bufc = smem + (jt & 1) * TILE_F;
    // issue next tile's global loads early (latency hides under K-loop)
    float4 n0, n1, n2, n3;
    if (jt + 1 < NTILE) {
      const float* src = bias_row + (size_t)(jt + 1) * 4096;
      n0 = *(const float4*)(src + (size_t)t * 4);
      n1 = *(const float4*)(src + (size_t)(256 + t) * 4);
      n2 = *(const float4*)(src + (size_t)(512 + t) * 4);
      n3 = *(const float4*)(src + (size_t)(768 + t) * 4);
    }
    int j0 = jt * JTILE + jl * 4;
    const float* kp = kb + j0;
    const float* vp = vb + j0;
    float s0 = 0.f, s1 = 0.f, s2 = 0.f, s3 = 0.f;
#pragma unroll
    for (int d = 0; d < 32; d++) {
      float4 kv = *(const float4*)(kp + (size_t)d * LSEQ);
      float4 bb = *(const float4*)&bufc[d * BIASLD + jl * 4];
      float qd = qsh[d];
      s0 += qd * (kv.x + bb.x);
      s1 += qd * (kv.y + bb.y);
      s2 += qd * (kv.z + bb.z);
      s3 += qd * (kv.w + bb.w);
    }
    float p0 = __expf(s0 * INV_SQRT_DK);
    float p1 = __expf(s1 * INV_SQRT_DK);
    float p2 = __expf(s2 * INV_SQRT_DK);
    float p3 = __expf(s3 * INV_SQRT_DK);
    l_part += (p0 + p1) + (p2 + p3);
    *(float4*)&arow[j0] = make_float4(p0, p1, p2, p3);  // unnormalized, rescaled later

    // write next tile into the OTHER buffer now (protected by last tile's barrier);
    // the V-loop below then hides the LDS-write drain
    if (jt + 1 < NTILE) {
      float* bufn = smem + ((jt + 1) & 1) * TILE_F;
      int jr, d0;
      jr = t >> 3; d0 = (t & 7) * 4;
      bufn[(d0 + 0) * BIASLD + jr] = n0.x; bufn[(d0 + 1) * BIASLD + jr] = n0.y;
      bufn[(d0 + 2) * BIASLD + jr] = n0.z; bufn[(d0 + 3) * BIASLD + jr] = n0.w;
      jr = (256 + t) >> 3;
      bufn[(d0 + 0) * BIASLD + jr] = n1.x; bufn[(d0 + 1) * BIASLD + jr] = n1.y;
      bufn[(d0 + 2) * BIASLD + jr] = n1.z; bufn[(d0 + 3) * BIASLD + jr] = n1.w;
      jr = (512 + t) >> 3;
      bufn[(d0 + 0) * BIASLD + jr] = n2.x; bufn[(d0 + 1) * BIASLD + jr] = n2.y;
      bufn[(d0 + 2) * BIASLD + jr] = n2.z; bufn[(d0 + 3) * BIASLD + jr] = n2.w;
      jr = (768 + t) >> 3;
      bufn[(d0 + 0) * BIASLD + jr] = n3.x; bufn[(d0 + 1) * BIASLD + jr] = n3.y;
      bufn[(d0 + 2) * BIASLD + jr] = n3.z; bufn[(d0 + 3) * BIASLD + jr] = n3.w;
    }

#pragma unroll
    for (int d = 0; d < 32; d++) {
      float4 vv = *(const float4*)(vp + (size_t)d * LSEQ);
      float4 bb = *(const float4*)&bufc[d * BIASLD + jl * 4];
      acc[d] += p0 * (vv.x + bb.x) + p1 * (vv.y + bb.y) +
                p2 * (vv.z + bb.z) + p3 * (vv.w + bb.w);
    }
    __syncthreads();
  }

  // per-head softmax denominator: reduce over the 32 jl lanes (half-wave)
  float l = l_part;
#pragma unroll
  for (int off = 16; off > 0; off >>= 1) l += __shfl_xor(l, off);
  float inv_l = 1.0f / l;

  // rescale own p values in place (L2/L3-warm: just written by this thread)
#pragma unroll
  for (int c = 0; c < 8; c++) {
    int jc = c * 128 + jl * 4;
    float4 pv = *(const float4*)&arow[jc];
    pv.x *= inv_l; pv.y *= inv_l; pv.z *= inv_l; pv.w *= inv_l;
    *(float4*)&arow[jc] = pv;
  }

  // cross-lane reduction of emb partials: scratch[h][d][33] overlapping bias bufs
  // (loop's final barrier guarantees all waves are done reading biasT)
#pragma unroll
  for (int d = 0; d < 32; d++)
    smem[hh * 1056 + d * 33 + jl] = acc[d] * inv_l;
  __syncthreads();
  float emb = 0.f;
  {
    const float* base = &smem[(t >> 5) * 1056 + (t & 31) * 33];
#pragma unroll
    for (int r = 0; r < 32; r++) emb += base[r];
  }
  __syncthreads();
  smem[EMB_OFF + t] = emb;  // emb vector (h*32+d ordering == fc input ordering)
  __syncthreads();

  // FC + bias + residual: thread t = output channel
  float o = fc_b[t];
  const float4* wrow = (const float4*)(fc_w + (size_t)t * DMODEL);
#pragma unroll
  for (int c = 0; c < 64; c++) {
    float4 wv = wrow[c];
    float4 ev = *(const float4*)&smem[EMB_OFF + c * 4];
    o += wv.x * ev.x + wv.y * ev.y + wv.z * ev.z + wv.w * ev.w;
  }
  o += hin[(size_t)blk * DMODEL + t];
  out[(size_t)blk * DMODEL + t] = o;
}

extern "C" void kernel_launch(void* const* d_in, const int* in_sizes, int n_in,
                              void* d_out, int out_size, void* d_ws, size_t ws_size,
                              hipStream_t stream) {
  const float* h = (const float*)d_in[0];
  const float* bias = (const float*)d_in[1];
  const float* w_qs = (const float*)d_in[2];
  const float* w_ks = (const float*)d_in[3];
  const float* w_vs = (const float*)d_in[4];
  const float* ln_g = (const float*)d_in[5];
  const float* ln_b = (const float*)d_in[6];
  const float* fc_w = (const float*)d_in[7];
  const float* fc_b = (const float*)d_in[8];
  float* out = (float*)d_out;
  float* attn_out = out + (size_t)BATCH * LSEQ * DMODEL;  // tuple: (out, attn)

  float* ws = (float*)d_ws;
  float* stats = ws;                                    // 4096 floats
  float* q_ws = ws + 4096;                              // 2048*256
  float* kT = q_ws + (size_t)BATCH * LSEQ * DMODEL;     // 2*256*1024 (transposed)
  float* vT = kT + (size_t)BATCH * LSEQ * DMODEL;       // 2*256*1024 (transposed)

  ln_stats_kernel<<<BATCH * LSEQ, 256, 0, stream>>>(h, stats);
  qkv_gemm_kernel<<<dim3(32, 12), 256, 0, stream>>>(h, stats, ln_g, ln_b, w_qs, w_ks,
                                                    w_vs, q_ws, kT, vT);
  attn_kernel<<<BATCH * LSEQ, 256, 0, stream>>>(q_ws, kT, vT, bias, h, fc_w, fc_b,
                                                out, attn_out);
}